// Round 6
// baseline (120.644 us; speedup 1.0000x reference)
//
#include <hip/hip_runtime.h>
#include <hip/hip_bf16.h>

#define NN 8192
#define FF 128
#define BM 128
#define BK 64
#define KS 8
#define KCH (NN / KS)      // 1024 K per block
#define NSTEP (KCH / BK)   // 16

typedef __attribute__((ext_vector_type(8))) short bf16x8;   // 8 bf16 (4 VGPR)
typedef __attribute__((ext_vector_type(4))) float f32x4;

__device__ __forceinline__ short f2bf(float f) {
  unsigned u = __float_as_uint(f);
  u += 0x7FFFu + ((u >> 16) & 1u);
  return (short)(u >> 16);
}
__device__ __forceinline__ float bf2f(short s) {
  return __uint_as_float(((unsigned)(unsigned short)s) << 16);
}

// ---- kernel 1: deg[i] = rowsum(adj)+1 ; dinv[i] = (deg+1e-8)^-0.5 ----
__global__ __launch_bounds__(256) void k_deg(const float* __restrict__ adj,
                                             float* __restrict__ dinv) {
  const int row = blockIdx.x;
  const float4* p = (const float4*)(adj + (size_t)row * NN);
  float s = 0.f;
#pragma unroll
  for (int it = 0; it < 8; ++it) {
    float4 v = p[it * 256 + threadIdx.x];
    s += (v.x + v.y) + (v.z + v.w);
  }
#pragma unroll
  for (int off = 32; off > 0; off >>= 1) s += __shfl_down(s, off, 64);
  __shared__ float partial[4];
  if ((threadIdx.x & 63) == 0) partial[threadIdx.x >> 6] = s;
  __syncthreads();
  if (threadIdx.x == 0) {
    float deg = (partial[0] + partial[1]) + (partial[2] + partial[3]) + 1.0f;
    dinv[row] = 1.0f / sqrtf(deg + 1e-8f);
  }
}

// ---- kernel 2: yT[f][i] = dinv[i] * x[i][f]  (bf16, transposed for NT GEMM) ----
__global__ __launch_bounds__(256) void k_scale_t(const float* __restrict__ x,
                                                 const float* __restrict__ dinv,
                                                 short* __restrict__ yT) {
  __shared__ float tile[64][129];
  const int r0 = blockIdx.x * 64;
  const int tid = threadIdx.x;
#pragma unroll
  for (int it = 0; it < 8; ++it) {
    int q = it * 256 + tid;
    int r = q >> 5;
    int c = q & 31;
    float4 v = ((const float4*)(x + (size_t)(r0 + r) * FF))[c];
    float d = dinv[r0 + r];
    tile[r][c * 4 + 0] = v.x * d;
    tile[r][c * 4 + 1] = v.y * d;
    tile[r][c * 4 + 2] = v.z * d;
    tile[r][c * 4 + 3] = v.w * d;
  }
  __syncthreads();
  const int f = tid >> 1;
  const int i0 = (tid & 1) * 32;
#pragma unroll
  for (int g = 0; g < 4; ++g) {
    bf16x8 o;
#pragma unroll
    for (int j = 0; j < 8; ++j) o[j] = f2bf(tile[i0 + g * 8 + j][f]);
    *(bf16x8*)(yT + (size_t)f * NN + r0 + i0 + g * 8) = o;
  }
}

// ---- kernel 3: zpart[ks] = adj[:, ksliced] @ y. K-split MFMA GEMM. ----
// 512 blocks (64 M-tiles x 8 K-slices) = exactly 2 resident blocks/CU.
// BM=128, BN=128(all of F), BK=64. 512 thr = 8 waves (2M x 4N), each wave a
// 64x32 output tile (8 accs). A: f32->bf16 via reg-stage into double-buffered
// LDS (36.9 KB, one barrier per K-step). B: yT is 2 MiB L2-resident -> loaded
// straight into registers (double-buffered, reloaded after the consuming MFMA
// cluster so L2 latency hides under the next phase). 16 MFMA : 8 ds_read.
__global__ __launch_bounds__(512, 4) void k_gemm(const float* __restrict__ adj,
                                                 const short* __restrict__ yT,
                                                 short* __restrict__ zpart) {
  __shared__ short As[2][BM][72];     // bf16, +8 pad
  const int tid = threadIdx.x;
  const int wave = tid >> 6;
  const int lane = tid & 63;
  const int mb = 63 - (int)(blockIdx.x & 63);   // reverse: read L3-warm rows first
  const int ks = blockIdx.x >> 6;
  const int row0 = mb * BM;
  const size_t kbase = (size_t)ks * KCH;

  // A staging map: 128 rows x 64 f32, 16 f32 (4 float4) per thread
  const int s_ar = tid >> 2;
  const int s_ac = (tid & 3) * 16;
  const float* pa = adj + (size_t)(row0 + s_ar) * NN + kbase + s_ac;

  const int wm = (wave >> 2) * 64;   // 0/64
  const int wn = (wave & 3) * 32;    // 0/32/64/96
  const int fr = lane & 15;
  const int kh = (lane >> 4) * 8;

  // B direct-load bases (yT rows = feature cols of the output)
  const short* pb0 = yT + (size_t)(wn + fr) * NN + kbase + kh;        // n=0
  const short* pb1 = pb0 + (size_t)16 * NN;                           // n=1

  f32x4 acc00 = {0.f,0.f,0.f,0.f}, acc01 = acc00, acc10 = acc00, acc11 = acc00;
  f32x4 acc20 = acc00, acc21 = acc00, acc30 = acc00, acc31 = acc00;

  float4 aR0, aR1, aR2, aR3;
  bf16x8 bX[4], bY[4];   // [n*2 + kk]

#define LOADA(koff) do {                                                       \
    aR0 = *(const float4*)(pa + (koff));                                       \
    aR1 = *(const float4*)(pa + (koff) + 4);                                   \
    aR2 = *(const float4*)(pa + (koff) + 8);                                   \
    aR3 = *(const float4*)(pa + (koff) + 12);                                  \
  } while (0)

#define LOADB(dst, koff) do {                                                  \
    dst[0] = *(const bf16x8*)(pb0 + (koff));                                   \
    dst[1] = *(const bf16x8*)(pb0 + (koff) + 32);                              \
    dst[2] = *(const bf16x8*)(pb1 + (koff));                                   \
    dst[3] = *(const bf16x8*)(pb1 + (koff) + 32);                              \
  } while (0)

#define STAGE(BUF) do {                                                        \
    bf16x8 lo_, hi_;                                                           \
    lo_[0] = f2bf(aR0.x); lo_[1] = f2bf(aR0.y);                                \
    lo_[2] = f2bf(aR0.z); lo_[3] = f2bf(aR0.w);                                \
    lo_[4] = f2bf(aR1.x); lo_[5] = f2bf(aR1.y);                                \
    lo_[6] = f2bf(aR1.z); lo_[7] = f2bf(aR1.w);                                \
    hi_[0] = f2bf(aR2.x); hi_[1] = f2bf(aR2.y);                                \
    hi_[2] = f2bf(aR2.z); hi_[3] = f2bf(aR2.w);                                \
    hi_[4] = f2bf(aR3.x); hi_[5] = f2bf(aR3.y);                                \
    hi_[6] = f2bf(aR3.z); hi_[7] = f2bf(aR3.w);                                \
    *(bf16x8*)&As[BUF][s_ar][s_ac]     = lo_;                                  \
    *(bf16x8*)&As[BUF][s_ar][s_ac + 8] = hi_;                                  \
  } while (0)

#define COMPUTE(BUF, breg) do {                                                \
    _Pragma("unroll")                                                          \
    for (int kk = 0; kk < 2; ++kk) {                                           \
      bf16x8 a0 = *(const bf16x8*)&As[BUF][wm +  0 + fr][kk * 32 + kh];        \
      bf16x8 a1 = *(const bf16x8*)&As[BUF][wm + 16 + fr][kk * 32 + kh];        \
      bf16x8 a2 = *(const bf16x8*)&As[BUF][wm + 32 + fr][kk * 32 + kh];        \
      bf16x8 a3 = *(const bf16x8*)&As[BUF][wm + 48 + fr][kk * 32 + kh];        \
      acc00 = __builtin_amdgcn_mfma_f32_16x16x32_bf16(a0, breg[kk],     acc00, 0, 0, 0); \
      acc01 = __builtin_amdgcn_mfma_f32_16x16x32_bf16(a0, breg[2 + kk], acc01, 0, 0, 0); \
      acc10 = __builtin_amdgcn_mfma_f32_16x16x32_bf16(a1, breg[kk],     acc10, 0, 0, 0); \
      acc11 = __builtin_amdgcn_mfma_f32_16x16x32_bf16(a1, breg[2 + kk], acc11, 0, 0, 0); \
      acc20 = __builtin_amdgcn_mfma_f32_16x16x32_bf16(a2, breg[kk],     acc20, 0, 0, 0); \
      acc21 = __builtin_amdgcn_mfma_f32_16x16x32_bf16(a2, breg[2 + kk], acc21, 0, 0, 0); \
      acc30 = __builtin_amdgcn_mfma_f32_16x16x32_bf16(a3, breg[kk],     acc30, 0, 0, 0); \
      acc31 = __builtin_amdgcn_mfma_f32_16x16x32_bf16(a3, breg[2 + kk], acc31, 0, 0, 0); \
    }                                                                          \
  } while (0)

  // prologue
  LOADA(0);
  STAGE(0);
  LOADA(BK);            // tile 1 -> regs
  LOADB(bX, 0);
  LOADB(bY, BK);
  __syncthreads();

  for (int step = 0; step < NSTEP; step += 2) {
    // even phase: compute buf0 (tile step) with bX
    if (step + 1 < NSTEP) STAGE(1);                       // regs = tile step+1
    if (step + 2 < NSTEP) LOADA((step + 2) * BK);         // issue under MFMAs
    COMPUTE(0, bX);
    if (step + 2 < NSTEP) LOADB(bX, (step + 2) * BK);     // reload after use
    __syncthreads();
    // odd phase: compute buf1 (tile step+1) with bY
    if (step + 2 < NSTEP) STAGE(0);                       // regs = tile step+2
    if (step + 3 < NSTEP) LOADA((step + 3) * BK);
    COMPUTE(1, bY);
    if (step + 3 < NSTEP) LOADB(bY, (step + 3) * BK);
    __syncthreads();
  }

  // epilogue: D layout col=lane&15, row=(lane>>4)*4+r ; store bf16 partials
  const int r4 = (lane >> 4) * 4;
  short* zp = zpart + ((size_t)ks << 20);   // slice stride 8192*128
#define STOREM(accn0, accn1, MOFF) do {                                        \
    _Pragma("unroll")                                                          \
    for (int r = 0; r < 4; ++r) {                                              \
      int gi = row0 + wm + (MOFF) + r4 + r;                                    \
      zp[(size_t)gi * FF + wn + fr]      = f2bf(accn0[r]);                     \
      zp[(size_t)gi * FF + wn + 16 + fr] = f2bf(accn1[r]);                     \
    }                                                                          \
  } while (0)
  STOREM(acc00, acc01, 0);
  STOREM(acc10, acc11, 16);
  STOREM(acc20, acc21, 32);
  STOREM(acc30, acc31, 48);
#undef STOREM
#undef LOADA
#undef LOADB
#undef STAGE
#undef COMPUTE
}

// ---- kernel 4: out = relu((dinv*(sum_ks zpart + dinv*x)) @ W) ----
__global__ __launch_bounds__(256) void k_out(const short* __restrict__ zpart,
                                             const float* __restrict__ x,
                                             const float* __restrict__ dinv,
                                             const float* __restrict__ w,
                                             float* __restrict__ out) {
  __shared__ float zs[16][128];
  const int r0 = blockIdx.x * 16;
  const int tid = threadIdx.x;
#pragma unroll
  for (int half = 0; half < 2; ++half) {
    int p = half * 256 + tid;
    int r = p >> 5;
    int c4 = p & 31;
    int gi = r0 + r;
    const short* base = zpart + (size_t)gi * FF + c4 * 4;
    float s0 = 0.f, s1 = 0.f, s2 = 0.f, s3 = 0.f;
#pragma unroll
    for (int sidx = 0; sidx < KS; ++sidx) {
      short4 v = *(const short4*)(base + ((size_t)sidx << 20));
      s0 += bf2f(v.x); s1 += bf2f(v.y); s2 += bf2f(v.z); s3 += bf2f(v.w);
    }
    float4 xv = *(const float4*)(x + (size_t)gi * FF + c4 * 4);
    float di = dinv[gi];
    float di2 = di * di;
    zs[r][c4 * 4 + 0] = di * s0 + di2 * xv.x;
    zs[r][c4 * 4 + 1] = di * s1 + di2 * xv.y;
    zs[r][c4 * 4 + 2] = di * s2 + di2 * xv.z;
    zs[r][c4 * 4 + 3] = di * s3 + di2 * xv.w;
  }
  __syncthreads();
  const int f = tid & 127;
  const int rg = (tid >> 7) * 8;
  float acc[8] = {0.f, 0.f, 0.f, 0.f, 0.f, 0.f, 0.f, 0.f};
#pragma unroll 4
  for (int k = 0; k < 128; ++k) {
    float wv = w[k * FF + f];
#pragma unroll
    for (int r = 0; r < 8; ++r) acc[r] += zs[rg + r][k] * wv;
  }
#pragma unroll
  for (int r = 0; r < 8; ++r) {
    out[(size_t)(r0 + rg + r) * FF + f] = fmaxf(acc[r], 0.0f);
  }
}

extern "C" void kernel_launch(void* const* d_in, const int* in_sizes, int n_in,
                              void* d_out, int out_size, void* d_ws, size_t ws_size,
                              hipStream_t stream) {
  const float* x   = (const float*)d_in[0];
  const float* adj = (const float*)d_in[1];
  const float* w   = (const float*)d_in[2];
  float* out = (float*)d_out;

  float* dinv  = (float*)d_ws;                                  // 32 KiB @ 0
  short* yT    = (short*)((char*)d_ws + 64 * 1024);             // 2 MiB bf16 [128][8192]
  short* zpart = (short*)((char*)d_ws + 4 * 1024 * 1024);       // 16 MiB bf16 [8][8192][128]

  k_deg    <<<NN,      256, 0, stream>>>(adj, dinv);
  k_scale_t<<<NN / 64, 256, 0, stream>>>(x, dinv, yT);
  k_gemm   <<<64 * KS, 512, 0, stream>>>(adj, yT, zpart);
  k_out    <<<NN / 16, 256, 0, stream>>>(zpart, x, dinv, w, out);
}

// Round 7
// 114.418 us; speedup vs baseline: 1.0544x; 1.0544x over previous
//
#include <hip/hip_runtime.h>
#include <hip/hip_bf16.h>

#define NN 8192
#define FF 128
#define BM 64
#define BK 64
#define KS 8
#define KCH (NN / KS)      // 1024 K per block
#define NSTEP (KCH / BK)   // 16

typedef __attribute__((ext_vector_type(8))) short bf16x8;   // 8 bf16 (4 VGPR)
typedef __attribute__((ext_vector_type(4))) float f32x4;

__device__ __forceinline__ short f2bf(float f) {
  unsigned u = __float_as_uint(f);
  u += 0x7FFFu + ((u >> 16) & 1u);
  return (short)(u >> 16);
}
__device__ __forceinline__ float bf2f(short s) {
  return __uint_as_float(((unsigned)(unsigned short)s) << 16);
}

// raw barrier: ds-ops drained (lgkmcnt(0)) but global loads stay IN FLIGHT
// across the barrier (unlike __syncthreads' vmcnt(0) drain). Loads are only
// consumed by the issuing wave, so counted compiler-auto vmcnt covers them.
#define BAR() do {                                              \
    asm volatile("s_waitcnt lgkmcnt(0)" ::: "memory");          \
    __builtin_amdgcn_s_barrier();                               \
  } while (0)

// ---- kernel 1: deg[i] = rowsum(adj)+1 ; dinv[i] = (deg+1e-8)^-0.5 ----
__global__ __launch_bounds__(256) void k_deg(const float* __restrict__ adj,
                                             float* __restrict__ dinv) {
  const int row = blockIdx.x;
  const float4* p = (const float4*)(adj + (size_t)row * NN);
  float s = 0.f;
#pragma unroll
  for (int it = 0; it < 8; ++it) {
    float4 v = p[it * 256 + threadIdx.x];
    s += (v.x + v.y) + (v.z + v.w);
  }
#pragma unroll
  for (int off = 32; off > 0; off >>= 1) s += __shfl_down(s, off, 64);
  __shared__ float partial[4];
  if ((threadIdx.x & 63) == 0) partial[threadIdx.x >> 6] = s;
  __syncthreads();
  if (threadIdx.x == 0) {
    float deg = (partial[0] + partial[1]) + (partial[2] + partial[3]) + 1.0f;
    dinv[row] = 1.0f / sqrtf(deg + 1e-8f);
  }
}

// ---- kernel 2: yT[f][i] = dinv[i] * x[i][f]  (bf16, transposed for NT GEMM) ----
__global__ __launch_bounds__(256) void k_scale_t(const float* __restrict__ x,
                                                 const float* __restrict__ dinv,
                                                 short* __restrict__ yT) {
  __shared__ float tile[64][129];
  const int r0 = blockIdx.x * 64;
  const int tid = threadIdx.x;
#pragma unroll
  for (int it = 0; it < 8; ++it) {
    int q = it * 256 + tid;
    int r = q >> 5;
    int c = q & 31;
    float4 v = ((const float4*)(x + (size_t)(r0 + r) * FF))[c];
    float d = dinv[r0 + r];
    tile[r][c * 4 + 0] = v.x * d;
    tile[r][c * 4 + 1] = v.y * d;
    tile[r][c * 4 + 2] = v.z * d;
    tile[r][c * 4 + 3] = v.w * d;
  }
  __syncthreads();
  const int f = tid >> 1;
  const int i0 = (tid & 1) * 32;
#pragma unroll
  for (int g = 0; g < 4; ++g) {
    bf16x8 o;
#pragma unroll
    for (int j = 0; j < 8; ++j) o[j] = f2bf(tile[i0 + g * 8 + j][f]);
    *(bf16x8*)(yT + (size_t)f * NN + r0 + i0 + g * 8) = o;
  }
}

// ---- kernel 3: zpart[ks] = adj[:, ksliced] @ y. K-split MFMA GEMM. ----
// 1024 blocks (128 M-tiles x 8 K-slices), 512 thr = 8 waves (2M x 4N),
// BM=64, BN=128(all), BK=64, LDS double-buffer. Phase order:
// LOAD(t+2) -> COMPUTE(t) -> STAGE(t+1) -> lgkmcnt(0)+raw s_barrier.
// Raw barrier keeps the prefetch loads in flight across phases (~2-phase
// latency cover); 2 blocks/CU overlap residual stalls.
__global__ __launch_bounds__(512, 4) void k_gemm(const float* __restrict__ adj,
                                                 const short* __restrict__ yT,
                                                 short* __restrict__ zpart) {
  __shared__ short As[2][BM][72];     // bf16, +8 pad
  __shared__ short Bs[2][128][72];
  const int tid = threadIdx.x;
  const int wave = tid >> 6;
  const int lane = tid & 63;
  const int mb = 127 - (int)(blockIdx.x & 127);   // reverse: read L3-warm rows first
  const int ks = blockIdx.x >> 7;
  const int row0 = mb * BM;
  const size_t kbase = (size_t)ks * KCH;

  // staging maps: A = 64 rows x 64 f32 (8 f32/thread); B = 128 rows x 64 bf16
  const int s_ar = tid >> 3;
  const int s_ac = (tid & 7) * 8;
  const float* pa  = adj + (size_t)(row0 + s_ar) * NN + kbase + s_ac;
  const short* pb0 = yT + (size_t)s_ar * NN + kbase + s_ac;
  const short* pb1 = yT + (size_t)(s_ar + 64) * NN + kbase + s_ac;

  const int wm = (wave >> 2) * 32;   // 0/32
  const int wn = (wave & 3) * 32;    // 0/32/64/96
  const int fr = lane & 15;
  const int kh = (lane >> 4) * 8;

  f32x4 acc00 = {0.f,0.f,0.f,0.f}, acc01 = acc00, acc10 = acc00, acc11 = acc00;

  float4 aXlo, aXhi, aYlo, aYhi;
  bf16x8 bX0, bX1, bY0, bY1;

#define LOADT(alo, ahi, b0v, b1v, koff) do {                                   \
    alo = *(const float4*)(pa + (koff));                                       \
    ahi = *(const float4*)(pa + (koff) + 4);                                   \
    b0v = *(const bf16x8*)(pb0 + (koff));                                      \
    b1v = *(const bf16x8*)(pb1 + (koff));                                      \
  } while (0)

#define STAGE(BUF, alo, ahi, b0v, b1v) do {                                    \
    bf16x8 ap_;                                                                \
    ap_[0] = f2bf(alo.x); ap_[1] = f2bf(alo.y);                                \
    ap_[2] = f2bf(alo.z); ap_[3] = f2bf(alo.w);                                \
    ap_[4] = f2bf(ahi.x); ap_[5] = f2bf(ahi.y);                                \
    ap_[6] = f2bf(ahi.z); ap_[7] = f2bf(ahi.w);                                \
    *(bf16x8*)&As[BUF][s_ar][s_ac] = ap_;                                      \
    *(bf16x8*)&Bs[BUF][s_ar][s_ac] = b0v;                                      \
    *(bf16x8*)&Bs[BUF][s_ar + 64][s_ac] = b1v;                                 \
  } while (0)

#define COMPUTE(BUF) do {                                                      \
    _Pragma("unroll")                                                          \
    for (int kk = 0; kk < 2; ++kk) {                                           \
      bf16x8 a0 = *(const bf16x8*)&As[BUF][wm + fr][kk * 32 + kh];             \
      bf16x8 a1 = *(const bf16x8*)&As[BUF][wm + 16 + fr][kk * 32 + kh];        \
      bf16x8 b0 = *(const bf16x8*)&Bs[BUF][wn + fr][kk * 32 + kh];             \
      bf16x8 b1 = *(const bf16x8*)&Bs[BUF][wn + 16 + fr][kk * 32 + kh];        \
      acc00 = __builtin_amdgcn_mfma_f32_16x16x32_bf16(a0, b0, acc00, 0, 0, 0); \
      acc01 = __builtin_amdgcn_mfma_f32_16x16x32_bf16(a0, b1, acc01, 0, 0, 0); \
      acc10 = __builtin_amdgcn_mfma_f32_16x16x32_bf16(a1, b0, acc10, 0, 0, 0); \
      acc11 = __builtin_amdgcn_mfma_f32_16x16x32_bf16(a1, b1, acc11, 0, 0, 0); \
    }                                                                          \
  } while (0)

  // prologue: tile0 -> X -> LDS0; tile1 -> Y (in flight / landed later)
  LOADT(aXlo, aXhi, bX0, bX1, 0);
  LOADT(aYlo, aYhi, bY0, bY1, BK);
  STAGE(0, aXlo, aXhi, bX0, bX1);   // auto-counted vmcnt waits only X's loads
  BAR();

  for (int step = 0; step < NSTEP; step += 2) {
    // phase A: compute LDS0 (tile step); issue tile step+2 -> X; stage Y -> LDS1
    if (step + 2 < NSTEP) LOADT(aXlo, aXhi, bX0, bX1, (step + 2) * BK);
    COMPUTE(0);
    STAGE(1, aYlo, aYhi, bY0, bY1);
    BAR();
    // phase B: compute LDS1 (tile step+1); issue tile step+3 -> Y; stage X -> LDS0
    if (step + 3 < NSTEP) LOADT(aYlo, aYhi, bY0, bY1, (step + 3) * BK);
    COMPUTE(1);
    if (step + 2 < NSTEP) STAGE(0, aXlo, aXhi, bX0, bX1);
    BAR();
  }

  // epilogue: D layout col=lane&15, row=(lane>>4)*4+r ; store bf16 partials
  const int r4 = (lane >> 4) * 4;
  short* zp = zpart + ((size_t)ks << 20);   // slice stride 8192*128
#pragma unroll
  for (int r = 0; r < 4; ++r) {
    int gi0 = row0 + wm + r4 + r;
    int gi1 = gi0 + 16;
    zp[(size_t)gi0 * FF + wn + fr]      = f2bf(acc00[r]);
    zp[(size_t)gi0 * FF + wn + 16 + fr] = f2bf(acc01[r]);
    zp[(size_t)gi1 * FF + wn + fr]      = f2bf(acc10[r]);
    zp[(size_t)gi1 * FF + wn + 16 + fr] = f2bf(acc11[r]);
  }
#undef LOADT
#undef STAGE
#undef COMPUTE
}

// ---- kernel 4: out = relu((dinv*(sum_ks zpart + dinv*x)) @ W) ----
__global__ __launch_bounds__(256) void k_out(const short* __restrict__ zpart,
                                             const float* __restrict__ x,
                                             const float* __restrict__ dinv,
                                             const float* __restrict__ w,
                                             float* __restrict__ out) {
  __shared__ float zs[16][128];
  const int r0 = blockIdx.x * 16;
  const int tid = threadIdx.x;
#pragma unroll
  for (int half = 0; half < 2; ++half) {
    int p = half * 256 + tid;
    int r = p >> 5;
    int c4 = p & 31;
    int gi = r0 + r;
    const short* base = zpart + (size_t)gi * FF + c4 * 4;
    float s0 = 0.f, s1 = 0.f, s2 = 0.f, s3 = 0.f;
#pragma unroll
    for (int sidx = 0; sidx < KS; ++sidx) {
      short4 v = *(const short4*)(base + ((size_t)sidx << 20));
      s0 += bf2f(v.x); s1 += bf2f(v.y); s2 += bf2f(v.z); s3 += bf2f(v.w);
    }
    float4 xv = *(const float4*)(x + (size_t)gi * FF + c4 * 4);
    float di = dinv[gi];
    float di2 = di * di;
    zs[r][c4 * 4 + 0] = di * s0 + di2 * xv.x;
    zs[r][c4 * 4 + 1] = di * s1 + di2 * xv.y;
    zs[r][c4 * 4 + 2] = di * s2 + di2 * xv.z;
    zs[r][c4 * 4 + 3] = di * s3 + di2 * xv.w;
  }
  __syncthreads();
  const int f = tid & 127;
  const int rg = (tid >> 7) * 8;
  float acc[8] = {0.f, 0.f, 0.f, 0.f, 0.f, 0.f, 0.f, 0.f};
#pragma unroll 4
  for (int k = 0; k < 128; ++k) {
    float wv = w[k * FF + f];
#pragma unroll
    for (int r = 0; r < 8; ++r) acc[r] += zs[rg + r][k] * wv;
  }
#pragma unroll
  for (int r = 0; r < 8; ++r) {
    out[(size_t)(r0 + rg + r) * FF + f] = fmaxf(acc[r], 0.0f);
  }
}

extern "C" void kernel_launch(void* const* d_in, const int* in_sizes, int n_in,
                              void* d_out, int out_size, void* d_ws, size_t ws_size,
                              hipStream_t stream) {
  const float* x   = (const float*)d_in[0];
  const float* adj = (const float*)d_in[1];
  const float* w   = (const float*)d_in[2];
  float* out = (float*)d_out;

  float* dinv  = (float*)d_ws;                                  // 32 KiB @ 0
  short* yT    = (short*)((char*)d_ws + 64 * 1024);             // 2 MiB bf16 [128][8192]
  short* zpart = (short*)((char*)d_ws + 4 * 1024 * 1024);       // 16 MiB bf16 [8][8192][128]

  k_deg    <<<NN,      256, 0, stream>>>(adj, dinv);
  k_scale_t<<<NN / 64, 256, 0, stream>>>(x, dinv, yT);
  k_gemm   <<<128 * KS, 512, 0, stream>>>(adj, yT, zpart);
  k_out    <<<NN / 16, 256, 0, stream>>>(zpart, x, dinv, w, out);
}